// Round 1
// baseline (19730.081 us; speedup 1.0000x reference)
//
#include <hip/hip_runtime.h>
#include <hip/hip_bf16.h>

typedef unsigned short u16;
typedef short short8 __attribute__((ext_vector_type(8)));
typedef float f32x4 __attribute__((ext_vector_type(4)));

#define S_ 500
#define B_ 128
#define T_ 250
#define H_ 512
#define K_ 128
#define V_ 128
#define VOC 1000
#define NSTEP 249   // T-1

__device__ __forceinline__ float bf2f(u16 u) {
    union { unsigned int i; float f; } x; x.i = ((unsigned int)u) << 16; return x.f;
}
__device__ __forceinline__ u16 f2bf(float f) {
    union { float f; unsigned int i; } x; x.f = f;
    unsigned int r = x.i + 0x7fffu + ((x.i >> 16) & 1u);
    return (u16)(r >> 16);
}
__device__ __forceinline__ float sigm(float x) { return 1.f / (1.f + __expf(-x)); }
__device__ __forceinline__ f32x4 mfma16(short8 a, short8 b, f32x4 c) {
    return __builtin_amdgcn_mfma_f32_16x16x32_bf16(a, b, c, 0, 0, 0);
}

// ---------------- setup: pack weights into fragment-friendly bf16 layouts ----------------
// W1f[(k>>3)*2048 + n)*8 + (k&7)] = W1cat[k][n], K=1152 (emb512 | ctx128 | h1 512), N=2048
// W2f same scheme, K=640 (h1 512 | h2 128), N=512
// Woutf same scheme, K=256 (h2 128 | ctx 128), N=1024 (cols >=1000 zero)
__global__ __launch_bounds__(256) void pack_kernel(
    const float* __restrict__ w_ih1, const float* __restrict__ w_hh1,
    const float* __restrict__ b_ih1, const float* __restrict__ b_hh1,
    const float* __restrict__ w_ih2, const float* __restrict__ w_hh2,
    const float* __restrict__ b_ih2, const float* __restrict__ b_hh2,
    const float* __restrict__ w_out, const float* __restrict__ emb,
    u16* __restrict__ W1f, u16* __restrict__ W2f, u16* __restrict__ Woutf,
    float* __restrict__ bias1, float* __restrict__ bias2, u16* __restrict__ emb_bf)
{
    const int i0 = blockIdx.x * 256 + threadIdx.x;
    const int stride = gridDim.x * 256;
    for (int i = i0; i < 1152 * 2048; i += stride) {
        int k = i >> 11, n = i & 2047;
        float v = (k < 640) ? w_ih1[n * 640 + k] : w_hh1[n * 512 + (k - 640)];
        W1f[((size_t)(k >> 3) * 2048 + n) * 8 + (k & 7)] = f2bf(v);
    }
    for (int i = i0; i < 640 * 512; i += stride) {
        int k = i >> 9, n = i & 511;
        float v = (k < 512) ? w_ih2[n * 512 + k] : w_hh2[n * 128 + (k - 512)];
        W2f[((size_t)(k >> 3) * 512 + n) * 8 + (k & 7)] = f2bf(v);
    }
    for (int i = i0; i < 256 * 1024; i += stride) {
        int k = i >> 10, n = i & 1023;
        float v = (n < VOC) ? w_out[n * 256 + k] : 0.f;
        Woutf[((size_t)(k >> 3) * 1024 + n) * 8 + (k & 7)] = f2bf(v);
    }
    for (int i = i0; i < 2048; i += stride) bias1[i] = b_ih1[i] + b_hh1[i];
    for (int i = i0; i < 512; i += stride) bias2[i] = b_ih2[i] + b_hh2[i];
    for (int i = i0; i < VOC * H_; i += stride) emb_bf[i] = f2bf(emb[i]);
}

// key [S,B,K] f32 -> key_bf [B,S,K] bf16 ; values likewise
__global__ __launch_bounds__(256) void conv_kv_kernel(
    const float* __restrict__ key, const float* __restrict__ values,
    u16* __restrict__ key_bf, u16* __restrict__ val_bf)
{
    const int i0 = blockIdx.x * 256 + threadIdx.x;
    const int stride = gridDim.x * 256;
    for (int i = i0; i < S_ * B_ * K_; i += stride) {
        int s = i >> 14;            // / (128*128)
        int r = i & 16383;
        int b = r >> 7, k = r & 127;
        size_t d = ((size_t)b * S_ + s) * K_ + k;
        key_bf[d] = f2bf(key[i]);
        val_bf[d] = f2bf(values[i]);
    }
}

__global__ __launch_bounds__(256) void zero_kernel(u16* __restrict__ ubuf, int ucount,
                                                   float* __restrict__ fbuf, int fcount)
{
    const int i0 = blockIdx.x * 256 + threadIdx.x;
    const int stride = gridDim.x * 256;
    for (int i = i0; i < ucount; i += stride) ubuf[i] = 0;
    for (int i = i0; i < fcount; i += stride) fbuf[i] = 0.f;
}

// ---------------- per-step K1: gates1 = [emb|ctx|h1] @ W1cat + bias, LSTM1 pointwise -> h1,c1
// grid 64: blockIdx = jg*2+mh ; jg in [0,32) hidden-16-group, mh in {0,1} batch half.
// 4 waves = 4 gates (i,f,g,o). Wave tile [64,16], K=1152 via direct-global frags.
__global__ __launch_bounds__(256) void k1_kernel(
    const u16* __restrict__ emb_bf, const int* __restrict__ text,
    const u16* __restrict__ W1f, const float* __restrict__ bias1,
    const u16* __restrict__ CTcur, const u16* __restrict__ H1cur,
    float* __restrict__ c1, u16* __restrict__ H1nxt, int t)
{
    __shared__ float Gbuf[64][64];
    const int tid = threadIdx.x;
    const int lane = tid & 63, gt = tid >> 6;
    const int lrow = lane & 15, lk = lane >> 4;
    const int jg = blockIdx.x >> 1, mh = blockIdx.x & 1;
    const int n = 512 * gt + jg * 16 + lrow;

    int brow[4];
    const u16* aemb[4];
#pragma unroll
    for (int rt = 0; rt < 4; ++rt) {
        int b = mh * 64 + rt * 16 + lrow;
        brow[rt] = b;
        int tok = (t == 0) ? 0 : text[t * B_ + b];
        aemb[rt] = emb_bf + (size_t)tok * H_;
    }
    f32x4 acc[4] = {{0,0,0,0},{0,0,0,0},{0,0,0,0},{0,0,0,0}};

    // emb region: k in [0,512)
#pragma unroll 4
    for (int kc = 0; kc < 16; ++kc) {
        int k = kc * 32 + lk * 8;
        short8 bw = *reinterpret_cast<const short8*>(W1f + ((size_t)(k >> 3) * 2048 + n) * 8);
#pragma unroll
        for (int rt = 0; rt < 4; ++rt) {
            short8 a = *reinterpret_cast<const short8*>(aemb[rt] + k);
            acc[rt] = mfma16(a, bw, acc[rt]);
        }
    }
    // ctx region: k in [512,640)
#pragma unroll
    for (int kc = 16; kc < 20; ++kc) {
        int k = kc * 32 + lk * 8;
        short8 bw = *reinterpret_cast<const short8*>(W1f + ((size_t)(k >> 3) * 2048 + n) * 8);
#pragma unroll
        for (int rt = 0; rt < 4; ++rt) {
            short8 a = *reinterpret_cast<const short8*>(CTcur + brow[rt] * V_ + (k - 512));
            acc[rt] = mfma16(a, bw, acc[rt]);
        }
    }
    // h1 region: k in [640,1152)
#pragma unroll 4
    for (int kc = 20; kc < 36; ++kc) {
        int k = kc * 32 + lk * 8;
        short8 bw = *reinterpret_cast<const short8*>(W1f + ((size_t)(k >> 3) * 2048 + n) * 8);
#pragma unroll
        for (int rt = 0; rt < 4; ++rt) {
            short8 a = *reinterpret_cast<const short8*>(H1cur + brow[rt] * H_ + (k - 640));
            acc[rt] = mfma16(a, bw, acc[rt]);
        }
    }

    float bv = bias1[n];
#pragma unroll
    for (int rt = 0; rt < 4; ++rt)
#pragma unroll
        for (int j = 0; j < 4; ++j)
            Gbuf[rt * 16 + lk * 4 + j][gt * 16 + lrow] = acc[rt][j] + bv;
    __syncthreads();

    for (int u = tid; u < 1024; u += 256) {
        int rb = u >> 4, jj = u & 15;
        int b = mh * 64 + rb;
        int hj = jg * 16 + jj;
        float gi = Gbuf[rb][jj], gf = Gbuf[rb][16 + jj];
        float gg = Gbuf[rb][32 + jj], go = Gbuf[rb][48 + jj];
        float cold = c1[b * H_ + hj];
        float cn = sigm(gf) * cold + sigm(gi) * tanhf(gg);
        float hn = sigm(go) * tanhf(cn);
        c1[b * H_ + hj] = cn;
        H1nxt[b * H_ + hj] = f2bf(hn);
    }
}

// ---------------- per-step K2: gates2 = [h1|h2] @ W2cat + bias2, LSTM2 pointwise -> h2,c2
// grid 32: blockIdx = q*8+w ; w in [0,8) hidden-16-group (of 128), q in [0,4) row quarter.
// 4 waves = 4 gates, wave tile [32,16] (2 row-tiles), K=640.
__global__ __launch_bounds__(256) void k2_kernel(
    const u16* __restrict__ W2f, const float* __restrict__ bias2,
    const u16* __restrict__ H1nxt, const u16* __restrict__ H2cur,
    float* __restrict__ c2, u16* __restrict__ H2nxt)
{
    __shared__ float Gbuf[32][64];
    const int tid = threadIdx.x;
    const int lane = tid & 63, gt = tid >> 6;
    const int lrow = lane & 15, lk = lane >> 4;
    const int w = blockIdx.x & 7, q = blockIdx.x >> 3;
    const int n = 128 * gt + w * 16 + lrow;
    const int b0 = q * 32 + lrow, b1 = q * 32 + 16 + lrow;

    f32x4 acc[2] = {{0,0,0,0},{0,0,0,0}};
#pragma unroll 4
    for (int kc = 0; kc < 16; ++kc) {
        int k = kc * 32 + lk * 8;
        short8 bw = *reinterpret_cast<const short8*>(W2f + ((size_t)(k >> 3) * 512 + n) * 8);
        short8 a0 = *reinterpret_cast<const short8*>(H1nxt + b0 * H_ + k);
        short8 a1 = *reinterpret_cast<const short8*>(H1nxt + b1 * H_ + k);
        acc[0] = mfma16(a0, bw, acc[0]);
        acc[1] = mfma16(a1, bw, acc[1]);
    }
#pragma unroll
    for (int kc = 16; kc < 20; ++kc) {
        int k = kc * 32 + lk * 8;
        short8 bw = *reinterpret_cast<const short8*>(W2f + ((size_t)(k >> 3) * 512 + n) * 8);
        short8 a0 = *reinterpret_cast<const short8*>(H2cur + b0 * K_ + (k - 512));
        short8 a1 = *reinterpret_cast<const short8*>(H2cur + b1 * K_ + (k - 512));
        acc[0] = mfma16(a0, bw, acc[0]);
        acc[1] = mfma16(a1, bw, acc[1]);
    }

    float bv = bias2[n];
#pragma unroll
    for (int j = 0; j < 4; ++j) {
        Gbuf[lk * 4 + j][gt * 16 + lrow] = acc[0][j] + bv;
        Gbuf[16 + lk * 4 + j][gt * 16 + lrow] = acc[1][j] + bv;
    }
    __syncthreads();

    for (int u = tid; u < 512; u += 256) {
        int rb = u >> 4, jj = u & 15;
        int b = q * 32 + rb;
        int hj = w * 16 + jj;
        float gi = Gbuf[rb][jj], gf = Gbuf[rb][16 + jj];
        float gg = Gbuf[rb][32 + jj], go = Gbuf[rb][48 + jj];
        float cold = c2[b * K_ + hj];
        float cn = sigm(gf) * cold + sigm(gi) * tanhf(gg);
        float hn = sigm(go) * tanhf(cn);
        c2[b * K_ + hj] = cn;
        H2nxt[b * K_ + hj] = f2bf(hn);
    }
}

// ---------------- per-step K3: attention for one batch row per WG ----------------
__global__ __launch_bounds__(256) void k3_kernel(
    const u16* __restrict__ key_bf, const u16* __restrict__ val_bf,
    const int* __restrict__ lens, const u16* __restrict__ H2nxt,
    u16* __restrict__ CTnxt, u16* __restrict__ Hc_t)
{
    __shared__ float h2s[K_];
    __shared__ float ebuf[512];
    __shared__ float cbuf[2][V_];
    __shared__ float red[8];
    const int b = blockIdx.x, tid = threadIdx.x;
    const int len = lens[b];

    if (tid < K_) {
        u16 hv = H2nxt[b * K_ + tid];
        h2s[tid] = bf2f(hv);
        Hc_t[b * 256 + tid] = hv;         // h2 part of [h2|ctx] row
    }
    __syncthreads();

    for (int s = tid; s < 512; s += 256) {
        float e = -1e9f;
        if (s < S_) {
            const u16* kp = key_bf + ((size_t)b * S_ + s) * K_;
            float a = 0.f;
#pragma unroll
            for (int kk = 0; kk < K_; kk += 8) {
                short8 kv = *reinterpret_cast<const short8*>(kp + kk);
#pragma unroll
                for (int j = 0; j < 8; ++j)
                    a += bf2f((u16)kv[j]) * h2s[kk + j];
            }
            e = (s < len) ? a : -1e9f;
        }
        ebuf[s] = e;
    }
    __syncthreads();

    float m = fmaxf(ebuf[tid], ebuf[tid + 256]);
#pragma unroll
    for (int off = 32; off > 0; off >>= 1) m = fmaxf(m, __shfl_down(m, off));
    if ((tid & 63) == 0) red[tid >> 6] = m;
    __syncthreads();
    const float maxv = fmaxf(fmaxf(red[0], red[1]), fmaxf(red[2], red[3]));

    float psum = 0.f;
    for (int s = tid; s < 512; s += 256) {
        float pv = __expf(ebuf[s] - maxv);
        ebuf[s] = pv;
        psum += pv;
    }
#pragma unroll
    for (int off = 32; off > 0; off >>= 1) psum += __shfl_down(psum, off);
    if ((tid & 63) == 0) red[4 + (tid >> 6)] = psum;
    __syncthreads();
    const float rinv = 1.f / (red[4] + red[5] + red[6] + red[7]);

    const int v = tid & 127, half = tid >> 7;
    const u16* vp = val_bf + ((size_t)b * S_ + half * 250) * V_ + v;
    float part = 0.f;
#pragma unroll 2
    for (int s = 0; s < 250; ++s)
        part += ebuf[half * 250 + s] * bf2f(vp[(size_t)s * V_]);
    cbuf[half][v] = part;
    __syncthreads();

    if (tid < V_) {
        float ctx = (cbuf[0][tid] + cbuf[1][tid]) * rinv;
        u16 cb = f2bf(ctx);
        CTnxt[b * V_ + tid] = cb;
        Hc_t[b * 256 + K_ + tid] = cb;    // ctx part
    }
}

// ---------------- final: pred = Hc[31872,256] @ Wout^T + b_out, scattered to [B,T-1,VOC]
// grid 249*16 : mt = row-tile (128 rows), nt = 64-col tile of padded 1024 cols.
__global__ __launch_bounds__(256) void k4_kernel(
    const u16* __restrict__ Hc, const u16* __restrict__ Woutf,
    const float* __restrict__ b_out, float* __restrict__ out)
{
    const int bx = blockIdx.x;
    const int mt = bx >> 4, nt = bx & 15;
    const int tid = threadIdx.x;
    const int lane = tid & 63, g = tid >> 6;
    const int lrow = lane & 15, lk = lane >> 4;
    const int n = nt * 64 + g * 16 + lrow;
    const float bias = (n < VOC) ? b_out[n] : 0.f;

    f32x4 acc[8];
#pragma unroll
    for (int rt = 0; rt < 8; ++rt) acc[rt] = (f32x4){bias, bias, bias, bias};

#pragma unroll
    for (int kc = 0; kc < 8; ++kc) {
        int k = kc * 32 + lk * 8;
        short8 bw = *reinterpret_cast<const short8*>(Woutf + ((size_t)(k >> 3) * 1024 + n) * 8);
#pragma unroll
        for (int rt = 0; rt < 8; ++rt) {
            int R = mt * 128 + rt * 16 + lrow;
            short8 a = *reinterpret_cast<const short8*>(Hc + (size_t)R * 256 + k);
            acc[rt] = mfma16(a, bw, acc[rt]);
        }
    }
    if (n < VOC) {
#pragma unroll
        for (int rt = 0; rt < 8; ++rt)
#pragma unroll
            for (int j = 0; j < 4; ++j) {
                int R = mt * 128 + rt * 16 + lk * 4 + j;
                int tt = R >> 7, bb = R & 127;
                out[((size_t)bb * NSTEP + tt) * VOC + n] = acc[rt][j];
            }
    }
}

// ---------------- host ----------------
extern "C" void kernel_launch(void* const* d_in, const int* in_sizes, int n_in,
                              void* d_out, int out_size, void* d_ws, size_t ws_size,
                              hipStream_t stream)
{
    const float* key    = (const float*)d_in[0];
    const float* values = (const float*)d_in[1];
    const int*   lens   = (const int*)d_in[2];
    const int*   text   = (const int*)d_in[3];
    const float* emb    = (const float*)d_in[4];
    const float* w_ih1  = (const float*)d_in[5];
    const float* w_hh1  = (const float*)d_in[6];
    const float* b_ih1  = (const float*)d_in[7];
    const float* b_hh1  = (const float*)d_in[8];
    const float* w_ih2  = (const float*)d_in[9];
    const float* w_hh2  = (const float*)d_in[10];
    const float* b_ih2  = (const float*)d_in[11];
    const float* b_hh2  = (const float*)d_in[12];
    const float* w_out  = (const float*)d_in[13];
    const float* b_out  = (const float*)d_in[14];

    char* p = (char*)d_ws;
    auto alloc = [&](size_t bytes) -> char* {
        char* r = p;
        p += (bytes + 255) & ~(size_t)255;
        return r;
    };
    u16*   key_bf = (u16*)  alloc((size_t)B_ * S_ * K_ * 2);
    u16*   val_bf = (u16*)  alloc((size_t)B_ * S_ * V_ * 2);
    u16*   emb_bf = (u16*)  alloc((size_t)VOC * H_ * 2);
    u16*   W1f    = (u16*)  alloc((size_t)1152 * 2048 * 2);
    u16*   W2f    = (u16*)  alloc((size_t)640 * 512 * 2);
    u16*   Woutf  = (u16*)  alloc((size_t)256 * 1024 * 2);
    float* bias1  = (float*)alloc(2048 * 4);
    float* bias2  = (float*)alloc(512 * 4);
    u16*   CT     = (u16*)  alloc((size_t)2 * B_ * V_ * 2);
    u16*   H1     = (u16*)  alloc((size_t)2 * B_ * H_ * 2);
    u16*   H2     = (u16*)  alloc((size_t)2 * B_ * K_ * 2);
    float* c1     = (float*)alloc((size_t)B_ * H_ * 4);
    float* c2     = (float*)alloc((size_t)B_ * K_ * 4);
    u16*   Hc     = (u16*)  alloc((size_t)NSTEP * B_ * 256 * 2);
    (void)ws_size; (void)in_sizes; (void)n_in; (void)out_size;

    pack_kernel<<<512, 256, 0, stream>>>(w_ih1, w_hh1, b_ih1, b_hh1,
                                         w_ih2, w_hh2, b_ih2, b_hh2,
                                         w_out, emb, W1f, W2f, Woutf, bias1, bias2, emb_bf);
    conv_kv_kernel<<<4096, 256, 0, stream>>>(key, values, key_bf, val_bf);
    // zero state: CT(2*128*128) + H1(2*128*512) + H2(2*128*128) u16 contiguous?  They are
    // separate allocs; zero each region via one kernel on the combined spans.
    zero_kernel<<<128, 256, 0, stream>>>(CT, 2 * B_ * V_, c1, B_ * H_);
    zero_kernel<<<128, 256, 0, stream>>>(H1, 2 * B_ * H_, c2, B_ * K_);
    zero_kernel<<<128, 256, 0, stream>>>(H2, 2 * B_ * K_, (float*)Hc, 0); // Hc fully overwritten; dummy f

    for (int t = 0; t < NSTEP; ++t) {
        int cur = t & 1, nxt = cur ^ 1;
        k1_kernel<<<64, 256, 0, stream>>>(emb_bf, text, W1f, bias1,
                                          CT + (size_t)cur * B_ * V_,
                                          H1 + (size_t)cur * B_ * H_,
                                          c1,
                                          H1 + (size_t)nxt * B_ * H_, t);
        k2_kernel<<<32, 256, 0, stream>>>(W2f, bias2,
                                          H1 + (size_t)nxt * B_ * H_,
                                          H2 + (size_t)cur * B_ * K_,
                                          c2,
                                          H2 + (size_t)nxt * B_ * K_);
        k3_kernel<<<128, 256, 0, stream>>>(key_bf, val_bf, lens,
                                           H2 + (size_t)nxt * B_ * K_,
                                           CT + (size_t)nxt * B_ * V_,
                                           Hc + (size_t)t * B_ * 256);
    }
    k4_kernel<<<NSTEP * 16, 256, 0, stream>>>(Hc, Woutf, b_out, (float*)d_out);
}